// Round 4
// baseline (58.367 us; speedup 1.0000x reference)
//
#include <hip/hip_runtime.h>
#include <stdint.h>

#define B_   32
#define L_   8192
#define D_   128
#define KTOP 512
#define NBINS 4096
#define CAP  1024   // candidate capacity (sel[] size)

typedef float v4f __attribute__((ext_vector_type(4)));

// ---------------- Threefry-2x32, key = (0, 42), 20 rounds ----------------
// jax.random.key(42) -> key pair (0, 42); threefry_partitionable 32-bit path:
// bits(p) = x0 ^ x1 of block (hi=0, lo=p).
__device__ __forceinline__ uint32_t rotl32(uint32_t x, int d) {
    return (x << d) | (x >> (32 - d));
}

__device__ __forceinline__ uint32_t threefry_bits(uint32_t p) {
    const uint32_t k0 = 0u, k1 = 42u;
    const uint32_t k2 = 0x1BD11BDAu ^ k0 ^ k1;
    uint32_t x0 = 0u + k0;   // c0 + ks0
    uint32_t x1 = p + k1;    // c1 + ks1
#define TF_R(r) { x0 += x1; x1 = rotl32(x1, r); x1 ^= x0; }
    TF_R(13) TF_R(15) TF_R(26) TF_R(6)   x0 += k1; x1 += k2 + 1u;
    TF_R(17) TF_R(29) TF_R(16) TF_R(24)  x0 += k2; x1 += k0 + 2u;
    TF_R(13) TF_R(15) TF_R(26) TF_R(6)   x0 += k0; x1 += k1 + 3u;
    TF_R(17) TF_R(29) TF_R(16) TF_R(24)  x0 += k1; x1 += k2 + 4u;
    TF_R(13) TF_R(15) TF_R(26) TF_R(6)   x0 += k2; x1 += k0 + 5u;
#undef TF_R
    return x0 ^ x1;
}

// One block per batch row. Computes packed keys, finds a conservative
// threshold via ONE 12-bit histogram (refine loop for pathological ties),
// compacts <=1024 candidates, rank-positions them (no sort), writes indices
// (as float for output, as int list for the copy kernel).
__global__ __launch_bounds__(1024) void select_kernel(
        const float* __restrict__ probs, const float* __restrict__ mask,
        float* __restrict__ out_ind, int* __restrict__ ind_i32) {
    const int b    = blockIdx.x;
    const int tid  = threadIdx.x;
    const int lane = tid & 63;
    const int wid  = tid >> 6;

    __shared__ uint32_t hist[NBINS];       // 16 KB
    __shared__ uint64_t sel[CAP];          // 8 KB
    __shared__ uint32_t wtot[16];
    __shared__ uint32_t s_bin, s_above, s_candv, s_cnt;

    // ---- packed sort keys: (monotone(y) << 16) | (8191 - l) ----
    uint64_t K[8];
#pragma unroll
    for (int j = 0; j < 8; ++j) {
        const int l = j * 1024 + tid;
        const int p = b * L_ + l;
        const uint32_t bits = threefry_bits((uint32_t)p);
        const float U = __uint_as_float((bits >> 9) | 0x3F800000u) - 1.0f;
        const float g = -logf(-logf(U + 1e-20f) + 1e-20f);
        const float y = probs[p] / 0.1f + g + mask[p] * (-10000.0f);
        const uint32_t u = __float_as_uint(y);
        const uint32_t mono = u ^ ((u & 0x80000000u) ? 0xFFFFFFFFu : 0x80000000u);
        K[j] = ((uint64_t)mono << 16) | (uint32_t)(8191 - l);
    }

    // ---- threshold search: 12-bit digits, usually exits after level 0 ----
    uint64_t prefix = 0;
    uint32_t needed = KTOP;
    uint64_t thrlo  = 0;
    for (int level = 0; level < 4; ++level) {
        const int shift = 36 - level * 12;
        for (int i = tid; i < NBINS; i += 1024) hist[i] = 0u;
        __syncthreads();
#pragma unroll
        for (int j = 0; j < 8; ++j) {
            const bool match = (level == 0) || ((K[j] >> (shift + 12)) == prefix);
            if (match) atomicAdd(&hist[(uint32_t)(K[j] >> shift) & (NBINS - 1u)], 1u);
        }
        __syncthreads();

        // suffix scan: thread t owns bins 4t..4t+3
        const uint32_t h0 = hist[4 * tid + 0];
        const uint32_t h1 = hist[4 * tid + 1];
        const uint32_t h2 = hist[4 * tid + 2];
        const uint32_t h3 = hist[4 * tid + 3];
        const uint32_t ls = h0 + h1 + h2 + h3;
        uint32_t s = ls;
#pragma unroll
        for (int off = 1; off < 64; off <<= 1) {
            const uint32_t v = __shfl_down(s, off);
            if (lane + off < 64) s += v;
        }
        if (lane == 0) wtot[wid] = s;      // whole-wave sum
        __syncthreads();
        uint32_t after_waves = 0;
        for (int w = wid + 1; w < 16; ++w) after_waves += wtot[w];
        const uint32_t base = after_waves + (s - ls);  // sum of bins after my 4
        const uint32_t s3 = h3 + base;
        const uint32_t s2 = h2 + s3;
        const uint32_t s1 = h1 + s2;
        const uint32_t s0 = h0 + s1;
        if (s0 >= needed && s1 < needed)  { s_bin = 4u*tid+0u; s_above = s1;  s_candv = s0; }
        if (s1 >= needed && s2 < needed)  { s_bin = 4u*tid+1u; s_above = s2;  s_candv = s1; }
        if (s2 >= needed && s3 < needed)  { s_bin = 4u*tid+2u; s_above = s3;  s_candv = s2; }
        if (s3 >= needed && base < needed){ s_bin = 4u*tid+3u; s_above = base;s_candv = s3; }
        __syncthreads();

        const uint32_t T = s_bin;
        thrlo = ((prefix << 12) | T) << shift;          // conservative threshold
        const uint32_t G = s_candv + (KTOP - needed);   // global candidate count
        if (G <= CAP) break;                            // ~always at level 0
        prefix = (prefix << 12) | T;
        needed -= s_above;
        __syncthreads();
    }

    // ---- compact candidates (keys >= thrlo) ----
    if (tid == 0) s_cnt = 0u;
    __syncthreads();
#pragma unroll
    for (int j = 0; j < 8; ++j) {
        if (K[j] >= thrlo) {
            const uint32_t pos = atomicAdd(&s_cnt, 1u);
            sel[pos] = K[j];
        }
    }
    __syncthreads();
    const uint32_t nc = s_cnt;

    // ---- rank-position: r = #{candidates with larger key}; write r < KTOP ----
    if (tid < (int)nc) {
        const uint64_t mine = sel[tid];
        uint32_t r = 0;
        uint32_t i = 0;
        for (; i + 4 <= nc; i += 4) {
            r += (uint32_t)(sel[i]     > mine);
            r += (uint32_t)(sel[i + 1] > mine);
            r += (uint32_t)(sel[i + 2] > mine);
            r += (uint32_t)(sel[i + 3] > mine);
        }
        for (; i < nc; ++i) r += (uint32_t)(sel[i] > mine);
        if (r < KTOP) {
            const uint32_t idx = 8191u - (uint32_t)(mine & 0xFFFFu);
            out_ind[b * KTOP + r] = (float)idx;
            ind_i32[b * KTOP + r] = (int)idx;
        }
    }
}

// Pure streaming zero of the [B, L, D] f32 output (no loads, no branches).
// 4096 blocks x 256 threads x 8 v4f = 8,388,608 float4.
__global__ __launch_bounds__(256) void zero_kernel(float* __restrict__ out) {
    v4f* o = (v4f*)out;
    uint32_t i = blockIdx.x * 256u + threadIdx.x;
    const uint32_t stride = 4096u * 256u;
    const v4f z = {0.f, 0.f, 0.f, 0.f};
#pragma unroll
    for (int k = 0; k < 8; ++k) {
        __builtin_nontemporal_store(z, &o[i]);
        i += stride;
    }
}

// Copies the 512 selected rows per batch from reps over the zeros.
// Block = 256 threads = 8 rows (32 lanes/row, one v4f each).
// Grid = B_ * (KTOP/8) = 32 * 64 = 2048 blocks.
__global__ __launch_bounds__(256) void copy_kernel(
        const float* __restrict__ reps, const int* __restrict__ ind_i32,
        float* __restrict__ out) {
    const int b     = blockIdx.x >> 6;          // 64 blocks per batch
    const int group = blockIdx.x & 63;
    const int r     = group * 8 + (threadIdx.x >> 5);
    const int t     = threadIdx.x & 31;
    const int idx   = ind_i32[b * KTOP + r];
    const size_t off = ((size_t)b * L_ + idx) * D_ + (size_t)t * 4;
    const v4f v = *(const v4f*)(reps + off);
    __builtin_nontemporal_store(v, (v4f*)(out + off));
}

extern "C" void kernel_launch(void* const* d_in, const int* in_sizes, int n_in,
                              void* d_out, int out_size, void* d_ws, size_t ws_size,
                              hipStream_t stream) {
    const float* reps  = (const float*)d_in[0];
    const float* probs = (const float*)d_in[1];
    const float* mask  = (const float*)d_in[2];
    float* out     = (float*)d_out;
    float* out_ind = out + (size_t)B_ * L_ * D_;
    int* ind_i32   = (int*)d_ws;   // B_*KTOP ints = 64 KB

    hipLaunchKernelGGL(select_kernel, dim3(B_), dim3(1024), 0, stream,
                       probs, mask, out_ind, ind_i32);
    hipLaunchKernelGGL(zero_kernel, dim3(4096), dim3(256), 0, stream, out);
    hipLaunchKernelGGL(copy_kernel, dim3(B_ * (KTOP / 8)), dim3(256), 0, stream,
                       reps, ind_i32, out);
}